// Round 5
// baseline (250.715 us; speedup 1.0000x reference)
//
#include <hip/hip_runtime.h>

#define EXPC 0.25505654442163f  // (1/sqrt(32)) * log2(e)

typedef __attribute__((ext_vector_type(8))) short bfrag;   // 8 bf16
typedef __attribute__((ext_vector_type(4))) float ffrag;   // 4 f32 acc
typedef __attribute__((ext_vector_type(8))) unsigned int u8v;
typedef __attribute__((ext_vector_type(4))) unsigned int u4v;
typedef __attribute__((ext_vector_type(2))) unsigned int u2v;

__device__ __forceinline__ short f2bf(float x) {
  union { float f; unsigned u; } v; v.f = x;
  return (short)((v.u + 0x8000u) >> 16);  // round-half-up
}

__device__ __forceinline__ float bf2f(short s) {
  union { float f; unsigned u; } v;
  v.u = ((unsigned)(unsigned short)s) << 16;
  return v.f;
}

__device__ __forceinline__ unsigned int packbf(float a, float b) {
  return __builtin_amdgcn_perm(__float_as_uint(b) + 0x8000u,
                               __float_as_uint(a) + 0x8000u, 0x07060302u);
}

__device__ __forceinline__ bfrag cvtp(u8v x) {
  u4v r;
#pragma unroll
  for (int i = 0; i < 4; ++i)
    r[i] = __builtin_amdgcn_perm(x[2 * i + 1] + 0x8000u, x[2 * i] + 0x8000u, 0x07060302u);
  union { u4v u; bfrag b; } c; c.u = r; return c.b;
}

// ---- fused K+V projection v2 (verbatim from the 204us session) ----
__global__ __launch_bounds__(256, 4) void proj_kv(
    const float* __restrict__ kin, const float* __restrict__ Wk,
    const float* __restrict__ bk, const float* __restrict__ vin,
    const float* __restrict__ Wv, const float* __restrict__ bv,
    short* __restrict__ ko, short* __restrict__ vt) {
  const int t = threadIdx.x;
  const int lane = t & 63, wid = t >> 6;
  const int lrow = lane & 15, lq = lane >> 4;
  __shared__ __align__(16) char lds[18432];
  const int row4 = t >> 2, c4 = (t & 3) * 8;

  const bool isK = blockIdx.x < 512;
  if (isK) {
    const int bx = blockIdx.x >> 1, d0 = (blockIdx.x & 1) * 128;
    const int m0 = bx * 64;
    short* Ab = (short*)lds;
    short* Bb = (short*)(lds + 5120);
    short* tile = (short*)lds;
    ffrag acc[4][2] = {};
    u8v pa, pb0, pb1;
    pa  = *(const u8v*)(kin + (size_t)(m0 + row4) * 256 + c4);
    pb0 = *(const u8v*)(Wk + (size_t)(d0 + row4) * 256 + c4);
    pb1 = *(const u8v*)(Wk + (size_t)(d0 + 64 + row4) * 256 + c4);
    *(bfrag*)(Ab + row4 * 40 + c4) = cvtp(pa);
    *(bfrag*)(Bb + row4 * 40 + c4) = cvtp(pb0);
    *(bfrag*)(Bb + (64 + row4) * 40 + c4) = cvtp(pb1);
#pragma unroll 1
    for (int s = 0; s < 8; ++s) {
      __syncthreads();
      if (s < 7) {
        const int k1 = (s + 1) * 32;
        pa  = *(const u8v*)(kin + (size_t)(m0 + row4) * 256 + k1 + c4);
        pb0 = *(const u8v*)(Wk + (size_t)(d0 + row4) * 256 + k1 + c4);
        pb1 = *(const u8v*)(Wk + (size_t)(d0 + 64 + row4) * 256 + k1 + c4);
      }
      bfrag a[4], b[2];
#pragma unroll
      for (int i = 0; i < 4; ++i)
        a[i] = *(const bfrag*)(Ab + (i * 16 + lrow) * 40 + lq * 8);
#pragma unroll
      for (int j = 0; j < 2; ++j)
        b[j] = *(const bfrag*)(Bb + (wid * 32 + j * 16 + lrow) * 40 + lq * 8);
#pragma unroll
      for (int i = 0; i < 4; ++i)
#pragma unroll
        for (int j = 0; j < 2; ++j)
          acc[i][j] = __builtin_amdgcn_mfma_f32_16x16x32_bf16(a[i], b[j], acc[i][j], 0, 0, 0);
      __syncthreads();
      if (s < 7) {
        *(bfrag*)(Ab + row4 * 40 + c4) = cvtp(pa);
        *(bfrag*)(Bb + row4 * 40 + c4) = cvtp(pb0);
        *(bfrag*)(Bb + (64 + row4) * 40 + c4) = cvtp(pb1);
      }
    }
    __syncthreads();
#pragma unroll
    for (int j = 0; j < 2; ++j) {
      int dl = wid * 32 + j * 16 + lrow;
      float bs = bk[d0 + dl];
#pragma unroll
      for (int i = 0; i < 4; ++i)
#pragma unroll
        for (int r = 0; r < 4; ++r)
          tile[(i * 16 + lq * 4 + r) * 136 + dl] = f2bf(acc[i][j][r] + bs);
    }
    __syncthreads();
#pragma unroll
    for (int p = 0; p < 4; ++p) {
      int id2 = p * 256 + t;
      int row = id2 >> 4, c = id2 & 15;
      bfrag v = *(const bfrag*)(tile + row * 136 + c * 8);
      *(bfrag*)(ko + (size_t)(m0 + row) * 256 + d0 + c * 8) = v;
    }
  } else {
    const int t2 = blockIdx.x - 512;
    const int bx = t2 >> 1, d0 = (t2 & 1) * 128;
    const int n0 = bx * 64;
    short* Aw = (short*)lds;
    short* Bv = (short*)(lds + 10240);
    short* tile = (short*)lds;
    ffrag acc[2][4] = {};
    u8v pv, pw0, pw1;
    pw0 = *(const u8v*)(Wv + (size_t)(d0 + row4) * 256 + c4);
    pw1 = *(const u8v*)(Wv + (size_t)(d0 + 64 + row4) * 256 + c4);
    pv  = *(const u8v*)(vin + (size_t)(n0 + row4) * 256 + c4);
    *(bfrag*)(Aw + row4 * 40 + c4) = cvtp(pw0);
    *(bfrag*)(Aw + (64 + row4) * 40 + c4) = cvtp(pw1);
    *(bfrag*)(Bv + row4 * 40 + c4) = cvtp(pv);
#pragma unroll 1
    for (int s = 0; s < 8; ++s) {
      __syncthreads();
      if (s < 7) {
        const int k1 = (s + 1) * 32;
        pw0 = *(const u8v*)(Wv + (size_t)(d0 + row4) * 256 + k1 + c4);
        pw1 = *(const u8v*)(Wv + (size_t)(d0 + 64 + row4) * 256 + k1 + c4);
        pv  = *(const u8v*)(vin + (size_t)(n0 + row4) * 256 + k1 + c4);
      }
      bfrag a[2], b[4];
#pragma unroll
      for (int i = 0; i < 2; ++i)
        a[i] = *(const bfrag*)(Aw + (wid * 32 + i * 16 + lrow) * 40 + lq * 8);
#pragma unroll
      for (int j = 0; j < 4; ++j)
        b[j] = *(const bfrag*)(Bv + (j * 16 + lrow) * 40 + lq * 8);
#pragma unroll
      for (int i = 0; i < 2; ++i)
#pragma unroll
        for (int j = 0; j < 4; ++j)
          acc[i][j] = __builtin_amdgcn_mfma_f32_16x16x32_bf16(a[i], b[j], acc[i][j], 0, 0, 0);
      __syncthreads();
      if (s < 7) {
        *(bfrag*)(Aw + row4 * 40 + c4) = cvtp(pw0);
        *(bfrag*)(Aw + (64 + row4) * 40 + c4) = cvtp(pw1);
        *(bfrag*)(Bv + row4 * 40 + c4) = cvtp(pv);
      }
    }
    __syncthreads();
#pragma unroll
    for (int i = 0; i < 2; ++i)
#pragma unroll
      for (int r = 0; r < 4; ++r) {
        int dl = wid * 32 + i * 16 + lq * 4 + r;
        float bs = bv[d0 + dl];
#pragma unroll
        for (int j = 0; j < 4; ++j)
          tile[dl * 72 + j * 16 + lrow] = f2bf(acc[i][j][r] + bs);
      }
    __syncthreads();
    const int bt = n0 >> 10, sl0 = n0 & 1023;
#pragma unroll
    for (int p = 0; p < 4; ++p) {
      int id2 = p * 256 + t;
      int dl = id2 >> 3, c = id2 & 7;
      bfrag v = *(const bfrag*)(tile + dl * 72 + c * 8);
      *(bfrag*)(vt + (size_t)bt * 262144 + (size_t)(d0 + dl) * 1024 + sl0 + c * 8) = v;
    }
  }
}

// ---- attn v7: head-split halves (4 heads/block, 256 thr), grid 1024 ----
// Phases 1-2 as v3 per-wave streams; phase 3 = K-dim partial of x*Wo,
// combined across the two half-blocks via f32 atomicAdd into zeroed out.
// Rows >= L handled entirely by bcast_fill (no D-mode / colsum tail here).
__global__ __launch_bounds__(256, 4) void attn_half(
    const float* __restrict__ query, const float* __restrict__ Wq,
    const float* __restrict__ bq, const float* __restrict__ Wo,
    const float* __restrict__ bo, const short* __restrict__ K,
    const short* __restrict__ Vt, const int* __restrict__ mask,
    float* __restrict__ out) {
  const int lane = threadIdx.x & 63, wid = threadIdx.x >> 6;  // wid in [0,4)
  const int lrow = lane & 15, lq = lane >> 4;
  const int id = blockIdx.x;                  // 1024 = 32 qt x 16 bt x 2 hb
  const int hb = id & 1;
  const int bt = (((id >> 1) & 15) + (id >> 9)) & 15;  // decorrelate L per CU
  const int qt = id >> 5;
  const int q0 = qt * 32;
  const int L = mask[bt];
  const int h = hb * 4 + wid;                 // this wave's head
  const int nvalid = min(max(L - q0, 0), 32);
  if (nvalid <= 0) return;                    // rows >= L covered by bcast_fill

  __shared__ __align__(16) short qx[32 * 136];              // 32 rows x 128 local d
  __shared__ __align__(16) unsigned int ptbuf[4][16 * 36];  // per-wave P^T
  unsigned int* ptg = &ptbuf[wid][0];

  const short* Vb = Vt + ((size_t)bt * 8 + h) * 32768;  // [32][1024]
  float l_i[2];
  ffrag o[2][2] = {};  // o[g][dj]

  // ---- phase 1: Q projection (32 rows x this head's 32 cols) ----
  {
    const int n0 = h * 32;
    const float* X = query + ((size_t)bt * 1024 + q0) * 256;
    ffrag acc[2][2] = {};
    u8v xa[2], wb[2], xa_n[2], wb_n[2];
#pragma unroll
    for (int i = 0; i < 2; ++i)
      xa[i] = *(const u8v*)(X + (size_t)(i * 16 + lrow) * 256 + lq * 8);
#pragma unroll
    for (int j = 0; j < 2; ++j)
      wb[j] = *(const u8v*)(Wq + (size_t)(n0 + j * 16 + lrow) * 256 + lq * 8);
#pragma unroll 1
    for (int tt = 0; tt < 8; ++tt) {
      if (tt < 7) {
        const int kk = (tt + 1) * 32;
#pragma unroll
        for (int i = 0; i < 2; ++i)
          xa_n[i] = *(const u8v*)(X + (size_t)(i * 16 + lrow) * 256 + kk + lq * 8);
#pragma unroll
        for (int j = 0; j < 2; ++j)
          wb_n[j] = *(const u8v*)(Wq + (size_t)(n0 + j * 16 + lrow) * 256 + kk + lq * 8);
      }
      bfrag a[2], b[2];
#pragma unroll
      for (int i = 0; i < 2; ++i) a[i] = cvtp(xa[i]);
#pragma unroll
      for (int j = 0; j < 2; ++j) b[j] = cvtp(wb[j]);
#pragma unroll
      for (int i = 0; i < 2; ++i)
#pragma unroll
        for (int j = 0; j < 2; ++j)
          acc[i][j] = __builtin_amdgcn_mfma_f32_16x16x32_bf16(a[i], b[j], acc[i][j], 0, 0, 0);
#pragma unroll
      for (int i = 0; i < 2; ++i) xa[i] = xa_n[i];
#pragma unroll
      for (int j = 0; j < 2; ++j) wb[j] = wb_n[j];
    }
#pragma unroll
    for (int j = 0; j < 2; ++j) {
      float bs = bq[n0 + j * 16 + lrow];
#pragma unroll
      for (int i = 0; i < 2; ++i)
#pragma unroll
        for (int r = 0; r < 4; ++r)
          qx[(i * 16 + lq * 4 + r) * 136 + wid * 32 + j * 16 + lrow] =
              f2bf((acc[i][j][r] + bs) * EXPC);
    }
  }
  // no barrier: wave reads only its own columns until phase 3

  // ---- phase 2: S^T = K.Q^T; kf prefetched one chunk ahead (v3 pattern) ----
  {
    const short* Kb = K + (size_t)bt * 262144;  // [1024][256]
    bfrag qf[2];
#pragma unroll
    for (int g = 0; g < 2; ++g)
      qf[g] = *(const bfrag*)(qx + (g * 16 + lrow) * 136 + wid * 32 + lq * 8);

    const int nchunk = (L + 63) >> 6;
    float l_loc[2] = {0.f, 0.f};
    bfrag kf[4], kf_n[4];
#pragma unroll
    for (int f = 0; f < 4; ++f)
      kf[f] = *(const bfrag*)(Kb + (size_t)(f * 16 + lrow) * 256 + h * 32 + lq * 8);

#pragma unroll 1
    for (int c = 0; c < nchunk; ++c) {
      const int kc = c * 64;
      const ffrag zf = {0.f, 0.f, 0.f, 0.f};
      if (c + 1 < nchunk) {
#pragma unroll
        for (int f = 0; f < 4; ++f)
          kf_n[f] = *(const bfrag*)(Kb + (size_t)(kc + 64 + f * 16 + lrow) * 256 + h * 32 + lq * 8);
      }
      bfrag av[2][2];
#pragma unroll
      for (int dj = 0; dj < 2; ++dj)
#pragma unroll
        for (int b = 0; b < 2; ++b)
          av[dj][b] = *(const bfrag*)(Vb + (size_t)(dj * 16 + lrow) * 1024 + kc + b * 32 + lq * 8);

      ffrag st[2][4];
#pragma unroll
      for (int g = 0; g < 2; ++g)
#pragma unroll
        for (int f = 0; f < 4; ++f)
          st[g][f] = __builtin_amdgcn_mfma_f32_16x16x32_bf16(kf[f], qf[g], zf, 0, 0, 0);

      const bool fullc = (kc + 64 <= L);
#pragma unroll
      for (int g = 0; g < 2; ++g) {
        float p[4][4];
        if (fullc) {
#pragma unroll
          for (int f = 0; f < 4; ++f)
#pragma unroll
            for (int r = 0; r < 4; ++r) {
              p[f][r] = __builtin_amdgcn_exp2f(st[g][f][r]);
              l_loc[g] += p[f][r];
            }
        } else {
#pragma unroll
          for (int f = 0; f < 4; ++f)
#pragma unroll
            for (int r = 0; r < 4; ++r) {
              int kr = kc + f * 16 + lq * 4 + r;
              float pv = (kr < L) ? __builtin_amdgcn_exp2f(st[g][f][r]) : 0.f;
              p[f][r] = pv;
              l_loc[g] += pv;
            }
        }
#pragma unroll
        for (int f = 0; f < 4; ++f) {
          u2v w;
          w[0] = packbf(p[f][0], p[f][1]);
          w[1] = packbf(p[f][2], p[f][3]);
          *(u2v*)(ptg + lrow * 36 + 8 * f + 2 * lq) = w;
        }
#pragma unroll
        for (int b = 0; b < 2; ++b) {
          u4v pv = *(const u4v*)(ptg + lrow * 36 + 16 * b + 4 * lq);
          union { u4v u; bfrag bf; } pt; pt.u = pv;
#pragma unroll
          for (int dj = 0; dj < 2; ++dj)
            o[g][dj] = __builtin_amdgcn_mfma_f32_16x16x32_bf16(av[dj][b], pt.bf, o[g][dj], 0, 0, 0);
        }
      }
#pragma unroll
      for (int f = 0; f < 4; ++f) kf[f] = kf_n[f];
    }

#pragma unroll
    for (int g = 0; g < 2; ++g) {
      float rs = l_loc[g];
      rs += __shfl_xor(rs, 16);
      rs += __shfl_xor(rs, 32);
      l_i[g] = rs;
    }
  }

  // write x into qx (local cols): qrow = g*16+lrow, dlocal = wid*32 + dj*16 + 4*lq + r
#pragma unroll
  for (int g = 0; g < 2; ++g) {
    float rcp = 1.0f / l_i[g];
#pragma unroll
    for (int dj = 0; dj < 2; ++dj) {
      u2v w;
      w[0] = packbf(o[g][dj][0] * rcp, o[g][dj][1] * rcp);
      w[1] = packbf(o[g][dj][2] * rcp, o[g][dj][3] * rcp);
      *(u2v*)(qx + (g * 16 + lrow) * 136 + wid * 32 + dj * 16 + lq * 4) = w;
    }
  }
  __syncthreads();

  // ---- phase 3: partial out-projection over this half's 128 d, atomic combine ----
  {
    const int n0p = wid * 64;  // this wave's 64 output columns
    ffrag acc[2][4] = {};
#pragma unroll 1
    for (int tt = 0; tt < 4; ++tt) {
      const int k0 = tt * 32;
      bfrag a0 = *(const bfrag*)(qx + lrow * 136 + k0 + lq * 8);
      bfrag a1 = *(const bfrag*)(qx + (16 + lrow) * 136 + k0 + lq * 8);
#pragma unroll
      for (int j = 0; j < 4; ++j) {
        bfrag b = cvtp(*(const u8v*)(Wo + (size_t)(n0p + j * 16 + lrow) * 256 + hb * 128 + k0 + lq * 8));
        acc[0][j] = __builtin_amdgcn_mfma_f32_16x16x32_bf16(a0, b, acc[0][j], 0, 0, 0);
        acc[1][j] = __builtin_amdgcn_mfma_f32_16x16x32_bf16(a1, b, acc[1][j], 0, 0, 0);
      }
    }
#pragma unroll
    for (int j = 0; j < 4; ++j) {
      const int dcol = n0p + j * 16 + lrow;
      const float bs = hb ? 0.f : bo[dcol];
#pragma unroll
      for (int i = 0; i < 2; ++i)
#pragma unroll
        for (int r = 0; r < 4; ++r) {
          int qr = q0 + i * 16 + lq * 4 + r;
          if (qr < L)
            atomicAdd(out + ((size_t)bt * 1024 + qr) * 256 + dcol, acc[i][j][r] + bs);
        }
    }
  }
}

// ---- bcast_fill: rows >= L get softmax(uniform).V = colmean(V), projected ----
__global__ __launch_bounds__(256, 2) void bcast_fill(
    const short* __restrict__ Vt, const float* __restrict__ Wo,
    const float* __restrict__ bo, const int* __restrict__ mask,
    float* __restrict__ out) {
  const int bt = blockIdx.x;
  const int L = mask[bt];
  const int d = threadIdx.x;
  __shared__ float xm[256];
  {
    const int hh = d >> 5, dl = d & 31;
    const short* vr = Vt + ((size_t)bt * 8 + hh) * 32768 + dl * 1024;
    float s = 0.f;
#pragma unroll 4
    for (int i = 0; i < 1024; i += 8) {
      bfrag v = *(const bfrag*)(vr + i);
#pragma unroll
      for (int j = 0; j < 8; ++j) s += bf2f(v[j]);
    }
    xm[d] = s * (1.0f / 1024.0f);
  }
  __syncthreads();
  float acc = bo[d];
  const float* wr = Wo + (size_t)d * 256;
#pragma unroll 4
  for (int k = 0; k < 256; k += 4) {
    float4 w4 = *(const float4*)(wr + k);
    acc += xm[k] * w4.x + xm[k + 1] * w4.y + xm[k + 2] * w4.z + xm[k + 3] * w4.w;
  }
  float* ob = out + (size_t)bt * 1024 * 256 + d;
#pragma unroll 1
  for (int row = L; row < 1024; ++row)
    ob[(size_t)row * 256] = acc;
}

extern "C" void kernel_launch(void* const* d_in, const int* in_sizes, int n_in,
                              void* d_out, int out_size, void* d_ws, size_t ws_size,
                              hipStream_t stream) {
  const float* query = (const float*)d_in[0];
  const float* key   = (const float*)d_in[1];
  const float* value = (const float*)d_in[2];
  const int*   mask  = (const int*)d_in[3];
  const float* Wq = (const float*)d_in[4];
  const float* bq = (const float*)d_in[5];
  const float* Wk = (const float*)d_in[6];
  const float* bk = (const float*)d_in[7];
  const float* Wv = (const float*)d_in[8];
  const float* bv = (const float*)d_in[9];
  const float* Wo = (const float*)d_in[10];
  const float* bo = (const float*)d_in[11];
  float* out = (float*)d_out;

  // workspace: K bf16 (8 MB) + Vt bf16 (8 MB) = 16,777,216 bytes exactly
  short* k_ws  = (short*)d_ws;
  short* vt_ws = k_ws + 4194304;

  proj_kv<<<dim3(1024), 256, 0, stream>>>(key, Wk, bk, value, Wv, bv, k_ws, vt_ws);
  attn_half<<<dim3(1024), 256, 0, stream>>>(query, Wq, bq, Wo, bo,
                                            k_ws, vt_ws, mask, out);
  bcast_fill<<<dim3(16), 256, 0, stream>>>(vt_ws, Wo, bo, mask, out);
}